// Round 11
// baseline (276.341 us; speedup 1.0000x reference)
//
#include <hip/hip_runtime.h>

#define HALO 10
#define SWD 76   // per-wave staged row width (74 used, padded even)

typedef float v2f __attribute__((ext_vector_type(2)));

// 1D Gaussian, sigma=1.5, 11 taps, normalized (compile-time constants;
// matches the reference's fp32 window to ~1e-7 -- far under threshold)
#define G0 0.00102838f
#define G1 0.00759871f
#define G2 0.03600077f
#define G3 0.10936069f
#define G4 0.21300556f
#define G5 0.26601176f
#define G6 G4
#define G7 G3
#define G8 G2
#define G9 G1
#define G10 G0

// one column-pair tap on the u-array (sA) and d-array (sB)
#define HT2(QA, QB, WK)                                              \
    { amu += (QA) * (WK); asu += ((QA) * (QA)) * (WK);               \
      amd_ += (QB) * (WK); asd += ((QB) * (QB)) * (WK); }

// R11: u/d math on the R2-GREEN skeleton. Session discriminators:
//   R2 structure (two float LDS arrays, e-based v2f reads): green 2/2,
//     absmax 0.0 (Rounds 2, 9).
//   R3 structure (single interleaved {u,d} v2f LDS array): red 2/2 with
//     DIFFERENT wrong answers (0.0977, 0.1367) -> nondeterministic race
//     somewhere in its staging structure; unlocatable by inspection; dead.
// The u/d IDENTITIES are exact math (not the suspect), so keep R2's LDS
// staging byte-identical (same arrays, same indices, same halo pattern,
// same reads) and change ONLY the staged values: sA <- u=x+y, sB <- d=x-y.
// This deletes the cross-stream conv (hc) and all parity pack-movs:
//   h-conv: 4 packed v2f chains over column pairs w/ parity v2f weights
//   vertical: 4 scalar chains x 11 (44 regs, was 55)
//   epilogue: mux*muy=(A^2-B^2)/4, mux^2+muy^2=(A^2+B^2)/2,
//             sigx^2+sigy^2=(su+sd)/2-msum, sigxy=(su-sd)/4-muxy
// Control flow / NI rounding / pool / prefetch / grids: bit-identical to
// the green R9 source. ZERO local arrays in the hot path (SROA lesson).
__global__ __launch_bounds__(256, 3) void ssim_wave_kernel(
    const float* __restrict__ x, const float* __restrict__ y,
    float* __restrict__ xo, float* __restrict__ yo,
    float* __restrict__ acc, int H, int W, int ROWS, int do_pool)
{
    const int OH = H - HALO, OW = W - HALO;
    const int nc = blockIdx.z;
    const int tid = threadIdx.x;
    const int wave = tid >> 6, lane = tid & 63;
    const int col0 = blockIdx.x * 64;
    const int r0 = (blockIdx.y * 4 + wave) * ROWS;

    const int c = col0 + lane;
    const bool colvalid = (c < OW);
    const int cl = min(c, W - 1);
    const int chalo = min(col0 + 64 + lane, W - 1);

    const int n_out = min(ROWS, OH - r0);
    const int poolrows = do_pool ? min(ROWS, H - r0) : 0;
    const int n_iter = max(n_out > 0 ? n_out + HALO : 0, poolrows);

    const float* xp = x + (size_t)nc * H * W;
    const float* yp = y + (size_t)nc * H * W;

    __shared__ float sA[4][SWD];
    __shared__ float sB[4][SWD];
    float* myA = sA[wave];
    float* myB = sB[wave];

    // parity-adjusted 12-tap weights as NAMED scalars (R2-verified trick),
    // paired into v2f constants for the column-pair reads
    const int par = lane & 1;
    const float w2_0  = par ? 0.f : G0;
    const float w2_1  = par ? G0  : G1;
    const float w2_2  = par ? G1  : G2;
    const float w2_3  = par ? G2  : G3;
    const float w2_4  = par ? G3  : G4;
    const float w2_5  = par ? G4  : G5;
    const float w2_6  = par ? G5  : G6;
    const float w2_7  = par ? G6  : G7;
    const float w2_8  = par ? G7  : G8;
    const float w2_9  = par ? G8  : G9;
    const float w2_10 = par ? G9  : G10;
    const float w2_11 = par ? G10 : 0.f;
    v2f W0; W0.x = w2_0;  W0.y = w2_1;
    v2f W1; W1.x = w2_2;  W1.y = w2_3;
    v2f W2; W2.x = w2_4;  W2.y = w2_5;
    v2f W3; W3.x = w2_6;  W3.y = w2_7;
    v2f W4; W4.x = w2_8;  W4.y = w2_9;
    v2f W5; W5.x = w2_10; W5.y = w2_11;
    const int e = lane & ~1;

    // vertical shift registers: slot j holds h-values of input row o+j
    // 4 scalar chains: Au (Sw*u), Ad (Sw*d), Su (Sw*u^2), Sd (Sw*d^2)
    float Au0=0.f, Au1=0.f, Au2=0.f, Au3=0.f, Au4=0.f, Au5=0.f,
          Au6=0.f, Au7=0.f, Au8=0.f, Au9=0.f, Au10=0.f;
    float Ad0=0.f, Ad1=0.f, Ad2=0.f, Ad3=0.f, Ad4=0.f, Ad5=0.f,
          Ad6=0.f, Ad7=0.f, Ad8=0.f, Ad9=0.f, Ad10=0.f;
    float Su0=0.f, Su1=0.f, Su2=0.f, Su3=0.f, Su4=0.f, Su5=0.f,
          Su6=0.f, Su7=0.f, Su8=0.f, Su9=0.f, Su10=0.f;
    float Sd0=0.f, Sd1=0.f, Sd2=0.f, Sd3=0.f, Sd4=0.f, Sd5=0.f,
          Sd6=0.f, Sd7=0.f, Sd8=0.f, Sd9=0.f, Sd10=0.f;

    float ssim_sum = 0.f, cs_sum = 0.f;

    // depth-2 prefetch: a = row i (arrived), b = row i+1 (in flight)
    float ax = 0.f, ay = 0.f, ahx = 0.f, ahy = 0.f;
    float bx = 0.f, by = 0.f, bhx = 0.f, bhy = 0.f;
    float prevx = 0.f, prevy = 0.f;

    const int Wo = W >> 1;
    float* xop = xo + (size_t)nc * (H >> 1) * Wo + (col0 >> 1);
    float* yop = yo + (size_t)nc * (H >> 1) * Wo + (col0 >> 1);

    if (n_iter > 0) {
        {   // prologue: load rows r0 and r0+1
            const float* rx = xp + (size_t)r0 * W;
            const float* ry = yp + (size_t)r0 * W;
            ax = rx[cl]; ay = ry[cl];
            if (lane < HALO) { ahx = rx[chalo]; ahy = ry[chalo]; }
            const int r1 = min(r0 + 1, H - 1);
            const float* rx1 = xp + (size_t)r1 * W;
            const float* ry1 = yp + (size_t)r1 * W;
            bx = rx1[cl]; by = ry1[cl];
            if (lane < HALO) { bhx = rx1[chalo]; bhy = ry1[chalo]; }
        }
        const int NI = ((n_iter + 10) / 11) * 11;
        for (int ii = 0; ii < NI; ii += 11) {
#pragma unroll
            for (int u = 0; u < 11; ++u) {
                const int i = ii + u;

                // fused 2x2 avg-pool from the raw row registers (row i = a)
                if (do_pool && i < poolrows) {
                    float sx2 = ax + __shfl_xor(ax, 1, 64);
                    float sy2 = ay + __shfl_xor(ay, 1, 64);
                    if (i & 1) {
                        if (par == 0) {
                            const int pr = (r0 + i) >> 1;
                            xop[(size_t)pr * Wo + (lane >> 1)] = 0.25f * (prevx + sx2);
                            yop[(size_t)pr * Wo + (lane >> 1)] = 0.25f * (prevy + sy2);
                        }
                    } else { prevx = sx2; prevy = sy2; }
                }

                // stage row i: sA <- u = x+y, sB <- d = x-y
                // (addressing bit-identical to R2's green staging)
                myA[lane] = ax + ay; myB[lane] = ax - ay;
                if (lane < HALO) {
                    myA[64 + lane] = ahx + ahy;
                    myB[64 + lane] = ahx - ahy;
                }

                // issue loads for row i+2 into the just-consumed a-regs
                {
                    const int rr = min(r0 + i + 2, H - 1);
                    const float* rx = xp + (size_t)rr * W;
                    const float* ry = yp + (size_t)rr * W;
                    ax = rx[cl]; ay = ry[cl];
                    if (lane < HALO) { ahx = rx[chalo]; ahy = ry[chalo]; }
                }

                // horizontal 11-tap conv from 6 named float2 LDS loads/array
                const v2f* pa = (const v2f*)&myA[e];
                const v2f* pb = (const v2f*)&myB[e];
                const v2f qa0 = pa[0], qa1 = pa[1], qa2 = pa[2],
                          qa3 = pa[3], qa4 = pa[4], qa5 = pa[5];
                const v2f qb0 = pb[0], qb1 = pb[1], qb2 = pb[2],
                          qb3 = pb[3], qb4 = pb[4], qb5 = pb[5];
                v2f amu = {0.f, 0.f}, amd_ = {0.f, 0.f};
                v2f asu = {0.f, 0.f}, asd = {0.f, 0.f};
                HT2(qa0, qb0, W0)
                HT2(qa1, qb1, W1)
                HT2(qa2, qb2, W2)
                HT2(qa3, qb3, W3)
                HT2(qa4, qb4, W4)
                HT2(qa5, qb5, W5)
                const float hu  = amu.x + amu.y;    // Sw*u  (row i)
                const float hd  = amd_.x + amd_.y;  // Sw*d
                const float hsu = asu.x + asu.y;    // Sw*u^2
                const float hsd = asd.x + asd.y;    // Sw*d^2

                // shift in row i (renamed away under the unroll)
                Au0=Au1; Au1=Au2; Au2=Au3; Au3=Au4; Au4=Au5; Au5=Au6;
                Au6=Au7; Au7=Au8; Au8=Au9; Au9=Au10; Au10=hu;
                Ad0=Ad1; Ad1=Ad2; Ad2=Ad3; Ad3=Ad4; Ad4=Ad5; Ad5=Ad6;
                Ad6=Ad7; Ad7=Ad8; Ad8=Ad9; Ad9=Ad10; Ad10=hd;
                Su0=Su1; Su1=Su2; Su2=Su3; Su3=Su4; Su4=Su5; Su5=Su6;
                Su6=Su7; Su7=Su8; Su8=Su9; Su9=Su10; Su10=hsu;
                Sd0=Sd1; Sd1=Sd2; Sd2=Sd3; Sd3=Sd4; Sd4=Sd5; Sd5=Sd6;
                Sd6=Sd7; Sd7=Sd8; Sd8=Sd9; Sd9=Sd10; Sd10=hsd;

                // output row o = i-10: slot j holds rows o..o+10
                const int o = i - HALO;
                if (o >= 0 && o < n_out && colvalid) {
                    float A = Au0*G0; A += Au1*G1; A += Au2*G2; A += Au3*G3;
                    A += Au4*G4; A += Au5*G5; A += Au6*G6; A += Au7*G7;
                    A += Au8*G8; A += Au9*G9; A += Au10*G10;
                    float B = Ad0*G0; B += Ad1*G1; B += Ad2*G2; B += Ad3*G3;
                    B += Ad4*G4; B += Ad5*G5; B += Ad6*G6; B += Ad7*G7;
                    B += Ad8*G8; B += Ad9*G9; B += Ad10*G10;
                    float su = Su0*G0; su += Su1*G1; su += Su2*G2; su += Su3*G3;
                    su += Su4*G4; su += Su5*G5; su += Su6*G6; su += Su7*G7;
                    su += Su8*G8; su += Su9*G9; su += Su10*G10;
                    float sd = Sd0*G0; sd += Sd1*G1; sd += Sd2*G2; sd += Sd3*G3;
                    sd += Sd4*G4; sd += Sd5*G5; sd += Sd6*G6; sd += Sd7*G7;
                    sd += Sd8*G8; sd += Sd9*G9; sd += Sd10*G10;

                    const float a2 = A * A, b2 = B * B;
                    const float mu_xy = 0.25f * (a2 - b2);       // mux*muy
                    const float msum  = 0.5f  * (a2 + b2);       // mux^2+muy^2
                    const float sig_s  = 0.5f  * (su + sd) - msum;
                    const float sig_xy = 0.25f * (su - sd) - mu_xy;
                    const float c1 = 1e-4f, c2 = 9e-4f;
                    const float cs = (2.f * sig_xy + c2) * __builtin_amdgcn_rcpf(sig_s + c2);
                    const float ssim = (2.f * mu_xy + c1) * __builtin_amdgcn_rcpf(msum + c1) * cs;
                    ssim_sum += ssim;
                    cs_sum += cs;
                }

                // rotate prefetch roles: a <- row i+1, b <- row i+2 (in flight)
                {
                    float t;
                    t = ax;  ax = bx;   bx = t;
                    t = ay;  ay = by;   by = t;
                    t = ahx; ahx = bhx; bhx = t;
                    t = ahy; ahy = bhy; bhy = t;
                }
            }
        }
    }

    // wave-local reduction + one atomic pair per wave
#pragma unroll
    for (int off = 32; off > 0; off >>= 1) {
        ssim_sum += __shfl_down(ssim_sum, off, 64);
        cs_sum   += __shfl_down(cs_sum,   off, 64);
    }
    if (lane == 0) {
        atomicAdd(&acc[nc * 2 + 0], ssim_sum);
        atomicAdd(&acc[nc * 2 + 1], cs_sum);
    }
}

// Combine the 5 scales: prod_s val_s^{w_s}, mean over the 48 (n,c) pairs.
__global__ void finalize_kernel(const float* __restrict__ acc,
                                const float* __restrict__ weights,
                                float* __restrict__ out)
{
    int t = threadIdx.x;  // 64 threads
    float v = 0.f;
    if (t < 48) {
        float prod = 1.f;
#pragma unroll
        for (int s = 0; s < 5; ++s) {
            int O = (512 >> s) - HALO;
            float inv = 1.f / ((float)O * (float)O);
            float ssim = acc[s * 96 + t * 2 + 0] * inv;
            float cs   = acc[s * 96 + t * 2 + 1] * inv;
            float val = (s < 4) ? fmaxf(cs, 0.f) : ssim;  // mcs[:-1] + [ssim]
            prod *= powf(val, weights[s]);
        }
        v = prod;
    }
#pragma unroll
    for (int off = 32; off > 0; off >>= 1) v += __shfl_down(v, off, 64);
    if (t == 0) out[0] = v * (1.f / 48.f);
}

extern "C" void kernel_launch(void* const* d_in, const int* in_sizes, int n_in,
                              void* d_out, int out_size, void* d_ws, size_t ws_size,
                              hipStream_t stream) {
    const float* x = (const float*)d_in[0];       // (16,3,512,512)
    const float* y = (const float*)d_in[1];       // (16,3,512,512)
    const float* weights = (const float*)d_in[3]; // (5,)
    float* out = (float*)d_out;
    float* ws = (float*)d_ws;

    // workspace layout (floats):
    //   [0,480)   : acc[5 scales][48 nc][2]   (ssim_sum, cs_sum)
    //   [512, ..) : downsampled pyramid x/y per scale
    float* acc = ws;
    float* xs1 = ws + 512;
    float* ys1 = xs1 + (size_t)48 * 256 * 256;
    float* xs2 = ys1 + (size_t)48 * 256 * 256;
    float* ys2 = xs2 + (size_t)48 * 128 * 128;
    float* xs3 = ys2 + (size_t)48 * 128 * 128;
    float* ys3 = xs3 + (size_t)48 * 64 * 64;
    float* xs4 = ys3 + (size_t)48 * 64 * 64;
    float* ys4 = xs4 + (size_t)48 * 32 * 32;

    hipMemsetAsync(acc, 0, 480 * sizeof(float), stream);

    dim3 blk(256);
    // grid: (col strips of 64, row chunks of 4*ROWS, nc); 4 indep waves/block
    // (bit-identical to the 2/2-green R2/R9 launch configuration)
    ssim_wave_kernel<<<dim3(8, 2, 48), blk, 0, stream>>>(x, y, xs1, ys1, acc + 0 * 96, 512, 512, 64, 1);
    ssim_wave_kernel<<<dim3(4, 2, 48), blk, 0, stream>>>(xs1, ys1, xs2, ys2, acc + 1 * 96, 256, 256, 32, 1);
    ssim_wave_kernel<<<dim3(2, 2, 48), blk, 0, stream>>>(xs2, ys2, xs3, ys3, acc + 2 * 96, 128, 128, 16, 1);
    ssim_wave_kernel<<<dim3(1, 2, 48), blk, 0, stream>>>(xs3, ys3, xs4, ys4, acc + 3 * 96, 64, 64, 8, 1);
    ssim_wave_kernel<<<dim3(1, 1, 48), blk, 0, stream>>>(xs4, ys4, nullptr, nullptr, acc + 4 * 96, 32, 32, 8, 0);

    finalize_kernel<<<dim3(1), dim3(64), 0, stream>>>(acc, weights, out);
}